// Round 3
// baseline (219.846 us; speedup 1.0000x reference)
//
#include <hip/hip_runtime.h>
#include <hip/hip_bf16.h>
#include <stdint.h>

typedef __bf16 bf16x8 __attribute__((ext_vector_type(8)));
typedef float floatx4 __attribute__((ext_vector_type(4)));

// ---------------------------------------------------------------------------
// Async global->LDS 16B copy (wave-uniform LDS base + lane*16; per-lane
// global address OK).
// ---------------------------------------------------------------------------
__device__ __forceinline__ void async_copy16(void* lds, const void* g) {
    __builtin_amdgcn_global_load_lds(
        (const __attribute__((address_space(1))) unsigned int*)g,
        (__attribute__((address_space(3))) unsigned int*)lds,
        16, 0, 0);
}

// ---------------------------------------------------------------------------
// Fused prep, one dispatch (UNCHANGED — isolate the gemm change):
//   blocks [0, nConv)         : x fp32 -> bf16 (8 elems/thread, float4 loads)
//   blocks [nConv, nConv+1280): Wrot[o,d] = sum_k kron(K1,K2,K3)[d,k] W[o,k]
// ---------------------------------------------------------------------------
__global__ __launch_bounds__(256)
void prep(const float* __restrict__ x,
          const float* __restrict__ W,
          const float* __restrict__ K1,
          const float* __restrict__ K2,
          const float* __restrict__ K3,
          __hip_bfloat16* __restrict__ x_bf,
          __hip_bfloat16* __restrict__ Wrot,
          int nConv) {
    const int tid = threadIdx.x;

    if ((int)blockIdx.x < nConv) {
        const size_t i = ((size_t)blockIdx.x * 256 + tid) * 8;
        const float4 a = *(const float4*)(x + i);
        const float4 b = *(const float4*)(x + i + 4);
        bf16x8 v;
        v[0] = (__bf16)a.x; v[1] = (__bf16)a.y; v[2] = (__bf16)a.z; v[3] = (__bf16)a.w;
        v[4] = (__bf16)b.x; v[5] = (__bf16)b.y; v[6] = (__bf16)b.z; v[7] = (__bf16)b.w;
        *(bf16x8*)((__bf16*)x_bf + i) = v;
        return;
    }

    const int o = blockIdx.x - nConv;
    __shared__ __align__(16) float w0[1280];   // W row, then stage-2 result
    __shared__ __align__(16) float t1[1280];
    __shared__ __align__(16) float k3s[1600];
    __shared__ float k2s[64];
    __shared__ float k1s[16];

    for (int i = tid; i < 1280; i += 256) w0[i] = W[o * 1280 + i];
    for (int i = tid; i < 1600; i += 256) k3s[i] = K3[i];
    if (tid < 64) k2s[tid] = K2[tid];
    if (tid < 16) k1s[tid] = K1[tid];
    __syncthreads();

    for (int i = tid; i < 1280; i += 256) {
        const int p = i / 40, d3 = i % 40;
        const float4* w4 = (const float4*)(w0 + p * 40);
        const float4* k4 = (const float4*)(k3s + d3 * 40);
        float acc = 0.f;
#pragma unroll
        for (int t = 0; t < 10; ++t) {
            const float4 a = w4[t], b = k4[t];
            acc += a.x * b.x + a.y * b.y + a.z * b.z + a.w * b.w;
        }
        t1[i] = acc;
    }
    __syncthreads();

    for (int i = tid; i < 1280; i += 256) {
        const int d3 = i % 40, pd = i / 40;
        const int k1 = pd >> 3, d2 = pd & 7;
        float acc = 0.f;
#pragma unroll
        for (int k2 = 0; k2 < 8; ++k2) acc += t1[(k1 * 8 + k2) * 40 + d3] * k2s[d2 * 8 + k2];
        w0[i] = acc;
    }
    __syncthreads();

    for (int i = tid; i < 1280; i += 256) {
        const int d3 = i % 40, pd = i / 40;
        const int d1 = pd >> 3, d2 = pd & 7;
        float acc = 0.f;
#pragma unroll
        for (int k1 = 0; k1 < 4; ++k1) acc += w0[(k1 * 8 + d2) * 40 + d3] * k1s[d1 * 4 + k1];
        Wrot[(size_t)o * 1280 + i] = __float2bfloat16(acc);
    }
}

// ---------------------------------------------------------------------------
// Main GEMM r9: C[m,n] = sum_k A[m,k] * B[n,k]   (bf16 in, fp32 out/acc)
//
// r8 skeleton (4-phase fine interleave, counted vmcnt, dbuf, XOR swizzle,
// 256-block XCD-chunked grid) with ONE change: no forced lgkmcnt(0) drain.
//   - r8 pinned `s_waitcnt lgkmcnt(0)` before each MFMA cluster, serializing
//     the LDS-read drain (ph0/ph1: 72 reads/CU ~864 cyc) against the MFMA
//     pipe (776 cyc) -> measured 33% MfmaUtil. Our ds_reads are C++ loads,
//     NOT inline asm: the compiler's waitcnt pass inserts exact partial
//     lgkmcnt(N) at each MFMA use site, so later reads drain UNDER earlier
//     MFMAs (rule #18 only applies to inline-asm ds_reads).
//   - ph0/ph1 MFMA loops interchanged to j-outer/i-inner so consumption
//     follows read-issue order (af[0..3] then bf[0..4]): first column needs
//     reads 1-5, each next column +1 read. Per-acc accumulation order is
//     UNCHANGED (same phase, same k-slices) -> numerics identical to r8.
//   - sched_barrier(0) on both sides of each raw s_barrier: pins the phase's
//     ds_reads above the barrier and MFMAs below (no cross-barrier hoists).
//   - vmcnt ledger identical to r8 (proven): stage ph0[A0,A2,B0] ph1[B1,B2]
//     ph2[B3,B4] ph3[A1,A3]; waits vmcnt(5)@ph1, vmcnt(2)@ph3, never 0
//     mid-loop; tail drains vmcnt(0)@ph1 of last tile.
// ---------------------------------------------------------------------------
#define BM 256
#define BN 320
#define BK 64
#define AGRAN 2048   // BM*8 granules (16B each) per buffer = 32 KiB
#define BGRAN 2560   // BN*8 granules per buffer = 40 KiB

__global__ __launch_bounds__(512, 2)
void gemm_bt(const __hip_bfloat16* __restrict__ A,   // [M,K] bf16
             const __hip_bfloat16* __restrict__ B,   // [N,K] bf16
             float* __restrict__ C,                  // [M,N] fp32
             int M, int N, int K) {
    __shared__ bf16x8 As[2][AGRAN];   // 64 KiB
    __shared__ bf16x8 Bs[2][BGRAN];   // 80 KiB

    const int tid  = threadIdx.x;
    const int wave = tid >> 6;
    const int lane = tid & 63;
    const int q    = lane >> 4;
    const int r16  = lane & 15;
    const int wm   = wave >> 2;       // 0..1
    const int wn   = wave & 3;        // 0..3

    // XCD-partitioned tile assignment (grid = 64*4 = 256, 8 | 256)
    const int nTilesN = N / BN;               // 4
    const int chunkM  = (M / BM) >> 3;        // 8 M-tiles per XCD
    const int xcd = blockIdx.x & 7;
    const int s   = blockIdx.x >> 3;          // 0..31 within XCD
    const int bm  = xcd * chunkM + s / nTilesN;
    const int bn  = s % nTilesN;
    const int tileM = bm * BM, tileN = bn * BN;

    // Per-chunk global byte offsets (u32; A max ~42MB, B max ~3.3MB).
    // chunk c covers granules [c*512, c*512+512): row m = g>>3, phys slot
    // p = g&7 holds data k-granule kv = p ^ (m&7)  (XOR swizzle at source).
    uint32_t aoff[4], boff[5];
#pragma unroll
    for (int c = 0; c < 4; ++c) {
        const int g = c * 512 + tid;
        const int m = g >> 3, kv = (g & 7) ^ (m & 7);
        aoff[c] = (uint32_t)(((tileM + m) * K + kv * 8) * 2);
    }
#pragma unroll
    for (int c = 0; c < 5; ++c) {
        const int g = c * 512 + tid;
        const int m = g >> 3, kv = (g & 7) ^ (m & 7);
        boff[c] = (uint32_t)(((tileN + m) * K + kv * 8) * 2);
    }
    const char* Abase = (const char*)A;
    const char* Bbase = (const char*)B;

    // LDS fragment granule indices for k-slice 0; k-slice 1 = idx ^ 4
    // (kv=4|q and q<4 => (4|q)^x == (q^x)^4 for any x in 0..7).
    int ai[8], bi[5];
#pragma unroll
    for (int i = 0; i < 8; ++i) {
        const int m = wm * 128 + i * 16 + r16;
        ai[i] = m * 8 + (q ^ (m & 7));
    }
#pragma unroll
    for (int j = 0; j < 5; ++j) {
        const int n = wn * 80 + j * 16 + r16;
        bi[j] = n * 8 + (q ^ (n & 7));
    }

    floatx4 acc[8][5];
#pragma unroll
    for (int i = 0; i < 8; ++i)
#pragma unroll
        for (int j = 0; j < 5; ++j) acc[i][j] = (floatx4){0.f, 0.f, 0.f, 0.f};

    const int nk = K / BK;                    // 20

    // Prologue: stage tile 0 (9 loads/thread), full drain once, barrier.
#pragma unroll
    for (int c = 0; c < 4; ++c)
        async_copy16(&As[0][c * 512 + wave * 64], Abase + aoff[c]);
#pragma unroll
    for (int c = 0; c < 5; ++c)
        async_copy16(&Bs[0][c * 512 + wave * 64], Bbase + boff[c]);
    asm volatile("s_waitcnt vmcnt(0)" ::: "memory");
    __builtin_amdgcn_s_barrier();

    bf16x8 bf0[5], bf1[5], af[4];

    for (int t = 0; t < nk; ++t) {
        const int cur = t & 1, nxt = cur ^ 1;
        const uint32_t kb = (uint32_t)((t + 1) * BK * 2);
        const bool hn = (t + 1 < nk);

        // ---------------- phase 0: k-slice 0, rows i=0..3 ----------------
#pragma unroll
        for (int i = 0; i < 4; ++i) af[i] = As[cur][ai[i]];
#pragma unroll
        for (int j = 0; j < 5; ++j) bf0[j] = Bs[cur][bi[j]];
        if (hn) {
            async_copy16(&As[nxt][0 * 512 + wave * 64], Abase + aoff[0] + kb);
            async_copy16(&As[nxt][2 * 512 + wave * 64], Abase + aoff[2] + kb);
            async_copy16(&Bs[nxt][0 * 512 + wave * 64], Bbase + boff[0] + kb);
        }
        __builtin_amdgcn_sched_barrier(0);
        __builtin_amdgcn_s_barrier();
        __builtin_amdgcn_sched_barrier(0);
        __builtin_amdgcn_s_setprio(1);
#pragma unroll
        for (int j = 0; j < 5; ++j)
#pragma unroll
            for (int i = 0; i < 4; ++i)
                acc[i][j] = __builtin_amdgcn_mfma_f32_16x16x32_bf16(
                    af[i], bf0[j], acc[i][j], 0, 0, 0);
        __builtin_amdgcn_s_setprio(0);
        __builtin_amdgcn_sched_barrier(0);
        __builtin_amdgcn_s_barrier();

        // ---------------- phase 1: k-slice 1, rows i=0..3 ----------------
#pragma unroll
        for (int i = 0; i < 4; ++i) af[i] = As[cur][ai[i] ^ 4];
#pragma unroll
        for (int j = 0; j < 5; ++j) bf1[j] = Bs[cur][bi[j] ^ 4];
        if (hn) {
            async_copy16(&Bs[nxt][1 * 512 + wave * 64], Bbase + boff[1] + kb);
            async_copy16(&Bs[nxt][2 * 512 + wave * 64], Bbase + boff[2] + kb);
            asm volatile("s_waitcnt vmcnt(5)" ::: "memory");   // retire A1,A3(t)
        } else {
            asm volatile("s_waitcnt vmcnt(0)" ::: "memory");   // tail drain
        }
        __builtin_amdgcn_sched_barrier(0);
        __builtin_amdgcn_s_barrier();
        __builtin_amdgcn_sched_barrier(0);
        __builtin_amdgcn_s_setprio(1);
#pragma unroll
        for (int j = 0; j < 5; ++j)
#pragma unroll
            for (int i = 0; i < 4; ++i)
                acc[i][j] = __builtin_amdgcn_mfma_f32_16x16x32_bf16(
                    af[i], bf1[j], acc[i][j], 0, 0, 0);
        __builtin_amdgcn_s_setprio(0);
        __builtin_amdgcn_sched_barrier(0);
        __builtin_amdgcn_s_barrier();

        // ---------------- phase 2: k-slice 0, rows i=4..7 ----------------
#pragma unroll
        for (int i = 0; i < 4; ++i) af[i] = As[cur][ai[4 + i]];
        if (hn) {
            async_copy16(&Bs[nxt][3 * 512 + wave * 64], Bbase + boff[3] + kb);
            async_copy16(&Bs[nxt][4 * 512 + wave * 64], Bbase + boff[4] + kb);
        }
        __builtin_amdgcn_sched_barrier(0);
        __builtin_amdgcn_s_barrier();
        __builtin_amdgcn_sched_barrier(0);
        __builtin_amdgcn_s_setprio(1);
#pragma unroll
        for (int i = 0; i < 4; ++i)
#pragma unroll
            for (int j = 0; j < 5; ++j)
                acc[4 + i][j] = __builtin_amdgcn_mfma_f32_16x16x32_bf16(
                    af[i], bf0[j], acc[4 + i][j], 0, 0, 0);
        __builtin_amdgcn_s_setprio(0);
        __builtin_amdgcn_sched_barrier(0);
        __builtin_amdgcn_s_barrier();

        // ---------------- phase 3: k-slice 1, rows i=4..7 ----------------
#pragma unroll
        for (int i = 0; i < 4; ++i) af[i] = As[cur][ai[4 + i] ^ 4];
        if (hn) {
            async_copy16(&As[nxt][1 * 512 + wave * 64], Abase + aoff[1] + kb);
            async_copy16(&As[nxt][3 * 512 + wave * 64], Abase + aoff[3] + kb);
            asm volatile("s_waitcnt vmcnt(2)" ::: "memory");   // first-7 of t+1 land
        }
        __builtin_amdgcn_sched_barrier(0);
        __builtin_amdgcn_s_barrier();
        __builtin_amdgcn_sched_barrier(0);
        __builtin_amdgcn_s_setprio(1);
#pragma unroll
        for (int i = 0; i < 4; ++i)
#pragma unroll
            for (int j = 0; j < 5; ++j)
                acc[4 + i][j] = __builtin_amdgcn_mfma_f32_16x16x32_bf16(
                    af[i], bf1[j], acc[4 + i][j], 0, 0, 0);
        __builtin_amdgcn_s_setprio(0);
        __builtin_amdgcn_sched_barrier(0);
        __builtin_amdgcn_s_barrier();
    }

    // epilogue: C/D layout col=lane&15, row=quad*4+reg (m89/m91)
#pragma unroll
    for (int i = 0; i < 8; ++i) {
#pragma unroll
        for (int j = 0; j < 5; ++j) {
            const int col = tileN + wn * 80 + j * 16 + r16;
#pragma unroll
            for (int r = 0; r < 4; ++r) {
                const int row = tileM + wm * 128 + i * 16 + q * 4 + r;
                C[(size_t)row * N + col] = acc[i][j][r];
            }
        }
    }
}

// ---------------------------------------------------------------------------
extern "C" void kernel_launch(void* const* d_in, const int* in_sizes, int n_in,
                              void* d_out, int out_size, void* d_ws, size_t ws_size,
                              hipStream_t stream) {
    const float* x  = (const float*)d_in[0];  // [4,4096,1280] fp32
    const float* W  = (const float*)d_in[1];  // [1280,1280]  fp32
    const float* K1 = (const float*)d_in[2];  // [4,4]
    const float* K2 = (const float*)d_in[3];  // [8,8]
    const float* K3 = (const float*)d_in[4];  // [40,40]
    float* out = (float*)d_out;               // [4,4096,1280] fp32

    const int D = 1280;
    const int M = in_sizes[0] / D;            // 16384
    const int N = D, K = D;

    // ws layout: [0, M*K) bf16 x ; then [+, N*K) bf16 Wrot
    __hip_bfloat16* x_bf = (__hip_bfloat16*)d_ws;
    __hip_bfloat16* Wrot = x_bf + (size_t)M * K;

    const int nConv = (M * K) / (256 * 8);    // 10240
    prep<<<nConv + D, 256, 0, stream>>>(x, W, K1, K2, K3, x_bf, Wrot, nConv);
    gemm_bt<<<(M / BM) * (N / BN), 512, 0, stream>>>(x_bf, Wrot, out, M, N, K);
}